// Round 9
// baseline (335.025 us; speedup 1.0000x reference)
//
#include <hip/hip_runtime.h>
#include <math.h>

// OFPenalty: power-iteration eigen-penalty on AAT = W W^T per batch, never
// materializing AAT. Round 11: R3 (proven 274us) + even grid + early prefetch.
//  - Ledger: 8 structures all pin at 2.4-3.4 TB/s effective READ while
//    write-only = 6.9 TB/s; m13's 6.29 "copy" is R+W (read stream ~3.15).
//    Working theory: ~3.2-3.4 TB/s is this machine's practical read-stream
//    ceiling for this class. Optimize within it:
//    (1) NSPLIT 7->8: 512 blocks = exactly 2/CU, kills the 448-block tail
//        (192 CUs ran 2 blocks, 64 ran 1 then idled -> ~12% loss).
//        Block s owns chunks 6s..6s+5 (+chunk 48 for s==7, block-uniform).
//    (2) First two chunk prefetches issued BEFORE the normalize phase.
//    (3) Plain loads (R8: nontemporal was -3.5%).
//  - k_repack unchanged (known 60us). Accuracy-preserving structure kept
//    exactly (absmax 0.0 so far): per-step normalize, full w = M x2 pass.
// A: (64, 512, 28, 28) fp32 -> W: (64, 512, 784). x0: (64, 512, 1).

#define BB 64
#define CC 512
#define DD 784
#define NSPLIT 8        // blocks per batch; 512 blocks total = 2/CU exactly
#define F4PR 196        // float4 per row of A
#define BF4 100352      // float4 per batch matrix (512*784/4)
#define FEPS 1e-12f

typedef float f4v __attribute__((ext_vector_type(4)));

__device__ __forceinline__ void gload16(const float4* gp, float4* lp) {
    __builtin_amdgcn_global_load_lds(
        (const __attribute__((address_space(1))) void*)gp,
        (__attribute__((address_space(3))) void*)lp, 16, 0, 0);
}

__device__ __forceinline__ float blk_reduce(float s, float* red) {
    for (int off = 32; off; off >>= 1) s += __shfl_down(s, off, 64);
    int w = threadIdx.x >> 6;
    if ((threadIdx.x & 63) == 0) red[w] = s;
    __syncthreads();
    float t = red[0] + red[1] + red[2] + red[3];
    __syncthreads();                       // allow red[] reuse by caller
    return t;
}

// Repack A[b][c][d] -> T2[b][chq][c][dq], chq=d>>2 (0..195).
// Block = (rowblock of 16 c, b). Stage 16 full rows in LDS (50 KB, linear,
// global_load_lds), then write: each chq gets 16 c x 16B = 256B contiguous
// global segments. (unchanged from the 274us run)
__global__ __launch_bounds__(256, 3)
void k_repack(const float* __restrict__ A, float* __restrict__ T) {
    __shared__ float4 lds4[16 * F4PR];     // 3136 f4 = 50,176 B
    const int tid = threadIdx.x, lane = tid & 63, w = tid >> 6;
    const int b = blockIdx.y, c0 = blockIdx.x * 16;
    const float4* src4 = (const float4*)A + ((size_t)b * CC + c0) * F4PR;
#pragma unroll
    for (int i = 0; i < 12; i++)
        gload16(src4 + i * 256 + w * 64 + lane, lds4 + i * 256 + w * 64);
    if (w == 0) gload16(src4 + 3072 + lane, lds4 + 3072);
    __syncthreads();                        // drains vmcnt before barrier
    float4* dst4 = (float4*)T + (size_t)b * BF4;
#pragma unroll
    for (int j = 0; j < 13; j++) {
        int idx = j * 256 + tid;
        if (idx < 3136) {
            int chq = idx >> 4, i = idx & 15;     // chq in 0..195
            dst4[(size_t)chq * CC + c0 + i] = lds4[i * F4PR + chq];
        }
    }
}

// vout[b][s][c] = partial of (AAT_b * normalize(sum_p xin[b][p][:]))_c over
// chunks 6s..6s+5 (+48 for s==7). Wave w owns quad w of each chunk; lane
// owns rows c = lane + 64k. Two named register buffers, loads issued before
// the normalize phase and two chunks ahead thereafter.
template <bool RP>
__global__ __launch_bounds__(256, 2)
void k_step(const float* __restrict__ M, const float* __restrict__ xin,
            const int nparts, float* __restrict__ vout) {
    __shared__ float xs[CC];
    __shared__ float vws[4][CC];
    __shared__ float red[4];

    const int tid = threadIdx.x;
    const int b = blockIdx.y, s = blockIdx.x;   // s in 0..7
    const int lane = tid & 63, w = tid >> 6;
    const float4* Mb = (const float4*)M + (size_t)b * BF4;

    float xk[8];
    float vk[8] = {0.f, 0.f, 0.f, 0.f, 0.f, 0.f, 0.f, 0.f};

    auto load = [&](int ch, f4v* dst) {
        if (RP) {
            const f4v* g = (const f4v*)(Mb + (size_t)(ch * 4 + w) * CC + lane);
#pragma unroll
            for (int k = 0; k < 8; k++) dst[k] = g[64 * k];
        } else {
            const f4v* g = (const f4v*)(Mb + (size_t)lane * F4PR + ch * 4 + w);
#pragma unroll
            for (int k = 0; k < 8; k++) dst[k] = g[(size_t)64 * k * F4PR];
        }
    };
    auto computeq = [&](const f4v* a) {
        // u-phase: u4[dq] = sum_c A[c][quad] * xhat[c]
        f4v ua = {0.f, 0.f, 0.f, 0.f};
#pragma unroll
        for (int k = 0; k < 8; k++) {
            ua.x += a[k].x * xk[k]; ua.y += a[k].y * xk[k];
            ua.z += a[k].z * xk[k]; ua.w += a[k].w * xk[k];
        }
#pragma unroll
        for (int off = 1; off < 64; off <<= 1) {
            ua.x += __shfl_xor(ua.x, off, 64);
            ua.y += __shfl_xor(ua.y, off, 64);
            ua.z += __shfl_xor(ua.z, off, 64);
            ua.w += __shfl_xor(ua.w, off, 64);
        }
        // v-phase: vk[k] += A[c][quad] . u4, accumulated across chunks
#pragma unroll
        for (int k = 0; k < 8; k++)
            vk[k] += a[k].x * ua.x + a[k].y * ua.y +
                     a[k].z * ua.z + a[k].w * ua.w;
    };

    const int ch0 = s * 6;
    const bool x7 = (s == NSPLIT - 1);     // block 7 also owns chunk 48

    // issue the first two chunk tiles; normalize hides under them
    f4v ra[8], rb[8];
    load(ch0, ra);
    load(ch0 + 1, rb);

    // ---- phase A: normalize input (sum nparts partial segments)
    const float* xp = xin + (size_t)b * nparts * CC;
    float xv0 = 0.f, xv1 = 0.f;
    for (int p = 0; p < nparts; p++) {
        xv0 += xp[p * CC + tid];
        xv1 += xp[p * CC + tid + 256];
    }
    float ss = blk_reduce(xv0 * xv0 + xv1 * xv1, red);
    float rn = 1.0f / fmaxf(sqrtf(ss), FEPS);
    xs[tid] = xv0 * rn;
    xs[tid + 256] = xv1 * rn;
    __syncthreads();
#pragma unroll
    for (int k = 0; k < 8; k++) xk[k] = xs[lane + 64 * k];

    // ---- pipelined chunk walk (2 ahead), all register names static
    computeq(ra); load(ch0 + 2, ra);       // ch0
    computeq(rb); load(ch0 + 3, rb);       // ch0+1
    computeq(ra); load(ch0 + 4, ra);       // ch0+2
    computeq(rb); load(ch0 + 5, rb);       // ch0+3
    computeq(ra);                          // ch0+4
    if (x7) load(48, ra);
    computeq(rb);                          // ch0+5
    if (x7) computeq(ra);                  // chunk 48 (quads 192..195)

    // ---- cross-wave v reduction (quads 0..3 live on waves 0..3)
#pragma unroll
    for (int k = 0; k < 8; k++) vws[w][lane + 64 * k] = vk[k];
    __syncthreads();
    float* vp = vout + ((size_t)b * NSPLIT + s) * CC;
    vp[tid]       = vws[0][tid] + vws[1][tid] + vws[2][tid] + vws[3][tid];
    vp[tid + 256] = vws[0][tid + 256] + vws[1][tid + 256] +
                    vws[2][tid + 256] + vws[3][tid + 256];
}

// largest_b = <t5, x1>/<x1,x1>, x1 = t4/||t4||;  y = t5 - largest*x1
// t4, t5 are NSPLIT-way partial buffers [b][NSPLIT][512].
__global__ void k_mid(const float* __restrict__ t4, const float* __restrict__ t5,
                      float* __restrict__ acc, float* __restrict__ y) {
    __shared__ float red[4];
    int b = blockIdx.x;
    const float* p4 = t4 + (size_t)b * NSPLIT * CC;
    const float* p5 = t5 + (size_t)b * NSPLIT * CC;
    float a0 = 0.f, a1 = 0.f, b0 = 0.f, b1 = 0.f;
    for (int p = 0; p < NSPLIT; p++) {
        a0 += p4[p * CC + threadIdx.x]; a1 += p4[p * CC + threadIdx.x + 256];
        b0 += p5[p * CC + threadIdx.x]; b1 += p5[p * CC + threadIdx.x + 256];
    }
    float ss4 = blk_reduce(a0 * a0 + a1 * a1, red);
    float rn = 1.0f / fmaxf(sqrtf(ss4), FEPS);
    float x10 = a0 * rn, x11 = a1 * rn;
    float num = blk_reduce(b0 * x10 + b1 * x11, red);
    float den = blk_reduce(x10 * x10 + x11 * x11, red);
    float largest = num / den;
    float* yp = y + (size_t)b * CC;
    yp[threadIdx.x] = b0 - largest * x10;
    yp[threadIdx.x + 256] = b1 - largest * x11;
    if (threadIdx.x == 0) acc[b * 8 + 0] = largest;
}

// dotwx = <w, x2>, den2 = <x2,x2>, x2 = y/||y||. w is partial [b][NSPLIT][512].
__global__ void k_fin2(const float* __restrict__ w, const float* __restrict__ y,
                       float* __restrict__ acc) {
    __shared__ float red[4];
    int b = blockIdx.x;
    const float* wp = w + (size_t)b * NSPLIT * CC;
    const float* yp = y + (size_t)b * CC;
    float w0 = 0.f, w1 = 0.f;
    for (int p = 0; p < NSPLIT; p++) {
        w0 += wp[p * CC + threadIdx.x];
        w1 += wp[p * CC + threadIdx.x + 256];
    }
    float y0 = yp[threadIdx.x], y1 = yp[threadIdx.x + 256];
    float ssy = blk_reduce(y0 * y0 + y1 * y1, red);
    float rn = 1.0f / fmaxf(sqrtf(ssy), FEPS);
    float x20 = y0 * rn, x21 = y1 * rn;
    float dotwx = blk_reduce(w0 * x20 + w1 * x21, red);
    float den2 = blk_reduce(x20 * x20 + x21 * x21, red);
    if (threadIdx.x == 0) { acc[b * 8 + 1] = dotwx; acc[b * 8 + 2] = den2; }
}

__global__ void k_out(const float* __restrict__ acc, float* __restrict__ out) {
    int b = threadIdx.x;                   // 64 threads = 1 wave
    float largest = acc[b * 8 + 0];
    float dotwx   = acc[b * 8 + 1];
    float den2    = acc[b * 8 + 2];
    float tmp = (dotwx - largest * den2) / den2;
    float smallest = tmp + largest;
    float r = largest / smallest - 1.0f;
    float pen = r * r;                     // BETA = 1
    for (int off = 32; off; off >>= 1) pen += __shfl_down(pen, off, 64);
    if (b == 0) out[0] = pen / (float)BB;
}

extern "C" void kernel_launch(void* const* d_in, const int* in_sizes, int n_in,
                              void* d_out, int out_size, void* d_ws, size_t ws_size,
                              hipStream_t stream) {
    const float* A  = (const float*)d_in[0];
    const float* x0 = (const float*)d_in[1];
    float* out = (float*)d_out;
    float* ws = (float*)d_ws;

    float* acc = ws;                          // 512 floats (64 x 8)
    float* Y   = ws + 512;                    // BB*CC dense y
    float* PA  = Y + BB * CC;                 // BB*NSPLIT*CC partials
    float* PB  = PA + (size_t)BB * NSPLIT * CC;
    float* T   = PB + (size_t)BB * NSPLIT * CC;   // BB*CC*DD = 102.8 MB
    const size_t need =
        ((size_t)512 + BB * CC + 2 * (size_t)BB * NSPLIT * CC +
         (size_t)BB * CC * DD) * sizeof(float);

    dim3 gS(NSPLIT, BB);
    if (ws_size >= need) {
        k_repack<<<dim3(32, BB), 256, 0, stream>>>(A, T);
        k_step<true><<<gS, 256, 0, stream>>>(T, x0, 1, PA);        // t1
        k_step<true><<<gS, 256, 0, stream>>>(T, PA, NSPLIT, PB);   // t2
        k_step<true><<<gS, 256, 0, stream>>>(T, PB, NSPLIT, PA);   // t3
        k_step<true><<<gS, 256, 0, stream>>>(T, PA, NSPLIT, PB);   // t4
        k_step<true><<<gS, 256, 0, stream>>>(T, PB, NSPLIT, PA);   // t5
        k_mid<<<BB, 256, 0, stream>>>(PB, PA, acc, Y);             // largest, y
        k_step<true><<<gS, 256, 0, stream>>>(T, Y, 1, PB);         // w
        k_fin2<<<BB, 256, 0, stream>>>(PB, Y, acc);
    } else {
        k_step<false><<<gS, 256, 0, stream>>>(A, x0, 1, PA);
        k_step<false><<<gS, 256, 0, stream>>>(A, PA, NSPLIT, PB);
        k_step<false><<<gS, 256, 0, stream>>>(A, PB, NSPLIT, PA);
        k_step<false><<<gS, 256, 0, stream>>>(A, PA, NSPLIT, PB);
        k_step<false><<<gS, 256, 0, stream>>>(A, PB, NSPLIT, PA);
        k_mid<<<BB, 256, 0, stream>>>(PB, PA, acc, Y);
        k_step<false><<<gS, 256, 0, stream>>>(A, Y, 1, PB);
        k_fin2<<<BB, 256, 0, stream>>>(PB, Y, acc);
    }
    k_out<<<1, 64, 0, stream>>>(acc, out);
}

// Round 10
// 275.219 us; speedup vs baseline: 1.2173x; 1.2173x over previous
//
#include <hip/hip_runtime.h>
#include <math.h>

// OFPenalty: power-iteration eigen-penalty on AAT = W W^T per batch, never
// materializing AAT. Round 12: exact R3 revert + repack fused into step 1.
//  - Ledger: R3 (274us) is a local optimum; all schedule perturbations
//    regressed (nt +10, NSPLIT=8 +61, 3/CU 2-ahead +115, one-shot +58).
//    Read-dominated kernels plateau at ~3.0-3.4 TB/s effective on this
//    workload regardless of structure. Stop rescheduling; cut a pass.
//  - Fusion: step 1 reads A directly (strided register loads, the R1-class
//    ~2 TB/s pattern), computes t1 AND stores T2[b][chq][c] from the same
//    registers (coalesced 1KB/instr writes). Deletes repack's separate
//    103 MB read of A: repack(60)+step1(34)=94us -> one ~60-65us kernel.
//  - Steps 2..6 are R3's k_step<true>, byte-identical (quad-major T2,
//    NSPLIT=7, 1-ahead register pipeline, loads after normalize, lb(256,2)).
// A: (64, 512, 28, 28) fp32 -> W: (64, 512, 784). x0: (64, 512, 1).

#define BB 64
#define CC 512
#define DD 784
#define NSPLIT 7
#define NCHPS 7         // chunks per split; NSPLIT*NCHPS = 49 = DD/DCH
#define F4PR 196        // float4 per row of A
#define BF4 100352      // float4 per batch matrix (512*784/4)
#define FEPS 1e-12f

__device__ __forceinline__ float blk_reduce(float s, float* red) {
    for (int off = 32; off; off >>= 1) s += __shfl_down(s, off, 64);
    int w = threadIdx.x >> 6;
    if ((threadIdx.x & 63) == 0) red[w] = s;
    __syncthreads();
    float t = red[0] + red[1] + red[2] + red[3];
    __syncthreads();                       // allow red[] reuse by caller
    return t;
}

// Fused step 1: reads A natively (strided), writes T2[b][chq][c] (coalesced),
// and computes t1 partials vout[b][s][c] for xhat = normalize(x0).
// Wave w owns quad chq = 4*ch+w of chunks ch = 7s..7s+6; lane owns rows
// c = lane + 64k.
__global__ __launch_bounds__(256, 2)
void k_step1f(const float* __restrict__ A, const float* __restrict__ xin,
              float* __restrict__ T, float* __restrict__ vout) {
    __shared__ float xs[CC];
    __shared__ float vws[4][CC];
    __shared__ float red[4];

    const int tid = threadIdx.x;
    const int b = blockIdx.y, s = blockIdx.x;
    const int lane = tid & 63, w = tid >> 6;
    const float4* Ab = (const float4*)A + (size_t)b * BF4;
    float4* Tb = (float4*)T + (size_t)b * BF4;

    // ---- phase A: normalize x0
    const float* xp = xin + (size_t)b * CC;
    float xv0 = xp[tid], xv1 = xp[tid + 256];
    float ss = blk_reduce(xv0 * xv0 + xv1 * xv1, red);
    float rn = 1.0f / fmaxf(sqrtf(ss), FEPS);
    xs[tid] = xv0 * rn;
    xs[tid + 256] = xv1 * rn;
    __syncthreads();

    float xk[8];
#pragma unroll
    for (int k = 0; k < 8; k++) xk[k] = xs[lane + 64 * k];

    const int ch0 = s * NCHPS;
    float4 a[2][8];
    float vk[8] = {0.f, 0.f, 0.f, 0.f, 0.f, 0.f, 0.f, 0.f};

    auto load = [&](int ch, float4* dst) {
        const float4* g = Ab + (size_t)lane * F4PR + ch * 4 + w;
#pragma unroll
        for (int k = 0; k < 8; k++) dst[k] = g[(size_t)64 * k * F4PR];
    };

    load(ch0, a[0]);
#pragma unroll
    for (int j = 0; j < NCHPS; j++) {
        const int cb = j & 1;                      // static after full unroll
        if (j + 1 < NCHPS) load(ch0 + j + 1, a[cb ^ 1]);

        // store this chunk-quad to T2 (coalesced: lane -> consecutive c)
        {
            float4* d = Tb + (size_t)((ch0 + j) * 4 + w) * CC + lane;
#pragma unroll
            for (int k = 0; k < 8; k++) d[64 * k] = a[cb][k];
        }

        // u-phase: u4[dq] = sum_c A[c][quad] * xhat[c]
        float4 ua = make_float4(0.f, 0.f, 0.f, 0.f);
#pragma unroll
        for (int k = 0; k < 8; k++) {
            ua.x += a[cb][k].x * xk[k]; ua.y += a[cb][k].y * xk[k];
            ua.z += a[cb][k].z * xk[k]; ua.w += a[cb][k].w * xk[k];
        }
#pragma unroll
        for (int off = 1; off < 64; off <<= 1) {
            ua.x += __shfl_xor(ua.x, off, 64);
            ua.y += __shfl_xor(ua.y, off, 64);
            ua.z += __shfl_xor(ua.z, off, 64);
            ua.w += __shfl_xor(ua.w, off, 64);
        }

        // v-phase: vk[k] += A[c][quad] . u4
#pragma unroll
        for (int k = 0; k < 8; k++)
            vk[k] += a[cb][k].x * ua.x + a[cb][k].y * ua.y +
                     a[cb][k].z * ua.z + a[cb][k].w * ua.w;
    }

    // ---- cross-wave v reduction
#pragma unroll
    for (int k = 0; k < 8; k++) vws[w][lane + 64 * k] = vk[k];
    __syncthreads();
    float* vp = vout + ((size_t)b * NSPLIT + s) * CC;
    vp[tid]       = vws[0][tid] + vws[1][tid] + vws[2][tid] + vws[3][tid];
    vp[tid + 256] = vws[0][tid + 256] + vws[1][tid + 256] +
                    vws[2][tid + 256] + vws[3][tid + 256];
}

// vout[b][s][c] = partial of (AAT_b * normalize(sum_p xin[b][p][:]))_c over
// chunks ch = s*7 .. s*7+6. RP: quad-major T2; else A directly (fallback).
// Wave w owns quad w of each chunk; lane owns rows c = lane + 64k.
// (byte-identical to the proven 274us R3 kernel)
template <bool RP>
__global__ __launch_bounds__(256, 2)
void k_step(const float* __restrict__ M, const float* __restrict__ xin,
            const int nparts, float* __restrict__ vout) {
    __shared__ float xs[CC];
    __shared__ float vws[4][CC];
    __shared__ float red[4];

    const int tid = threadIdx.x;
    const int b = blockIdx.y, s = blockIdx.x;
    const int lane = tid & 63, w = tid >> 6;
    const float4* Mb = (const float4*)M + (size_t)b * BF4;

    // ---- phase A: normalize input (sum nparts partial segments)
    const float* xp = xin + (size_t)b * nparts * CC;
    float xv0 = 0.f, xv1 = 0.f;
    for (int p = 0; p < nparts; p++) {
        xv0 += xp[p * CC + tid];
        xv1 += xp[p * CC + tid + 256];
    }
    float ss = blk_reduce(xv0 * xv0 + xv1 * xv1, red);
    float rn = 1.0f / fmaxf(sqrtf(ss), FEPS);
    xs[tid] = xv0 * rn;
    xs[tid + 256] = xv1 * rn;
    __syncthreads();

    float xk[8];
#pragma unroll
    for (int k = 0; k < 8; k++) xk[k] = xs[lane + 64 * k];

    const int ch0 = s * NCHPS;
    float4 a[2][8];
    float vk[8] = {0.f, 0.f, 0.f, 0.f, 0.f, 0.f, 0.f, 0.f};

    auto load = [&](int ch, float4* dst) {
        if (RP) {
            const float4* g = Mb + (size_t)(ch * 4 + w) * CC + lane;
#pragma unroll
            for (int k = 0; k < 8; k++) dst[k] = g[64 * k];
        } else {
            const float4* g = Mb + (size_t)lane * F4PR + ch * 4 + w;
#pragma unroll
            for (int k = 0; k < 8; k++) dst[k] = g[(size_t)64 * k * F4PR];
        }
    };

    load(ch0, a[0]);
#pragma unroll
    for (int j = 0; j < NCHPS; j++) {
        const int cb = j & 1;                      // static after full unroll
        if (j + 1 < NCHPS) load(ch0 + j + 1, a[cb ^ 1]);

        // u-phase: u4[dq] = sum_c A[c][ch*16+w*4+dq] * xhat[c]
        float4 ua = make_float4(0.f, 0.f, 0.f, 0.f);
#pragma unroll
        for (int k = 0; k < 8; k++) {
            ua.x += a[cb][k].x * xk[k]; ua.y += a[cb][k].y * xk[k];
            ua.z += a[cb][k].z * xk[k]; ua.w += a[cb][k].w * xk[k];
        }
#pragma unroll
        for (int off = 1; off < 64; off <<= 1) {
            ua.x += __shfl_xor(ua.x, off, 64);
            ua.y += __shfl_xor(ua.y, off, 64);
            ua.z += __shfl_xor(ua.z, off, 64);
            ua.w += __shfl_xor(ua.w, off, 64);
        }

        // v-phase: vk[k] += A[c][quad] . u4, accumulated across chunks
#pragma unroll
        for (int k = 0; k < 8; k++)
            vk[k] += a[cb][k].x * ua.x + a[cb][k].y * ua.y +
                     a[cb][k].z * ua.z + a[cb][k].w * ua.w;
    }

    // ---- cross-wave v reduction (quads 0..3 live on waves 0..3)
#pragma unroll
    for (int k = 0; k < 8; k++) vws[w][lane + 64 * k] = vk[k];
    __syncthreads();
    float* vp = vout + ((size_t)b * NSPLIT + s) * CC;
    vp[tid]       = vws[0][tid] + vws[1][tid] + vws[2][tid] + vws[3][tid];
    vp[tid + 256] = vws[0][tid + 256] + vws[1][tid + 256] +
                    vws[2][tid + 256] + vws[3][tid + 256];
}

// largest_b = <t5, x1>/<x1,x1>, x1 = t4/||t4||;  y = t5 - largest*x1
// t4, t5 are 7-way partial buffers [b][7][512].
__global__ void k_mid(const float* __restrict__ t4, const float* __restrict__ t5,
                      float* __restrict__ acc, float* __restrict__ y) {
    __shared__ float red[4];
    int b = blockIdx.x;
    const float* p4 = t4 + (size_t)b * NSPLIT * CC;
    const float* p5 = t5 + (size_t)b * NSPLIT * CC;
    float a0 = 0.f, a1 = 0.f, b0 = 0.f, b1 = 0.f;
    for (int p = 0; p < NSPLIT; p++) {
        a0 += p4[p * CC + threadIdx.x]; a1 += p4[p * CC + threadIdx.x + 256];
        b0 += p5[p * CC + threadIdx.x]; b1 += p5[p * CC + threadIdx.x + 256];
    }
    float ss4 = blk_reduce(a0 * a0 + a1 * a1, red);
    float rn = 1.0f / fmaxf(sqrtf(ss4), FEPS);
    float x10 = a0 * rn, x11 = a1 * rn;
    float num = blk_reduce(b0 * x10 + b1 * x11, red);
    float den = blk_reduce(x10 * x10 + x11 * x11, red);
    float largest = num / den;
    float* yp = y + (size_t)b * CC;
    yp[threadIdx.x] = b0 - largest * x10;
    yp[threadIdx.x + 256] = b1 - largest * x11;
    if (threadIdx.x == 0) acc[b * 8 + 0] = largest;
}

// dotwx = <w, x2>, den2 = <x2,x2>, x2 = y/||y||. w is partial [b][7][512].
__global__ void k_fin2(const float* __restrict__ w, const float* __restrict__ y,
                       float* __restrict__ acc) {
    __shared__ float red[4];
    int b = blockIdx.x;
    const float* wp = w + (size_t)b * NSPLIT * CC;
    const float* yp = y + (size_t)b * CC;
    float w0 = 0.f, w1 = 0.f;
    for (int p = 0; p < NSPLIT; p++) {
        w0 += wp[p * CC + threadIdx.x];
        w1 += wp[p * CC + threadIdx.x + 256];
    }
    float y0 = yp[threadIdx.x], y1 = yp[threadIdx.x + 256];
    float ssy = blk_reduce(y0 * y0 + y1 * y1, red);
    float rn = 1.0f / fmaxf(sqrtf(ssy), FEPS);
    float x20 = y0 * rn, x21 = y1 * rn;
    float dotwx = blk_reduce(w0 * x20 + w1 * x21, red);
    float den2 = blk_reduce(x20 * x20 + x21 * x21, red);
    if (threadIdx.x == 0) { acc[b * 8 + 1] = dotwx; acc[b * 8 + 2] = den2; }
}

__global__ void k_out(const float* __restrict__ acc, float* __restrict__ out) {
    int b = threadIdx.x;                   // 64 threads = 1 wave
    float largest = acc[b * 8 + 0];
    float dotwx   = acc[b * 8 + 1];
    float den2    = acc[b * 8 + 2];
    float tmp = (dotwx - largest * den2) / den2;
    float smallest = tmp + largest;
    float r = largest / smallest - 1.0f;
    float pen = r * r;                     // BETA = 1
    for (int off = 32; off; off >>= 1) pen += __shfl_down(pen, off, 64);
    if (b == 0) out[0] = pen / (float)BB;
}

extern "C" void kernel_launch(void* const* d_in, const int* in_sizes, int n_in,
                              void* d_out, int out_size, void* d_ws, size_t ws_size,
                              hipStream_t stream) {
    const float* A  = (const float*)d_in[0];
    const float* x0 = (const float*)d_in[1];
    float* out = (float*)d_out;
    float* ws = (float*)d_ws;

    float* acc = ws;                          // 512 floats (64 x 8)
    float* Y   = ws + 512;                    // BB*CC dense y
    float* PA  = Y + BB * CC;                 // BB*NSPLIT*CC partials
    float* PB  = PA + (size_t)BB * NSPLIT * CC;
    float* T   = PB + (size_t)BB * NSPLIT * CC;   // BB*CC*DD = 102.8 MB
    const size_t need =
        ((size_t)512 + BB * CC + 2 * (size_t)BB * NSPLIT * CC +
         (size_t)BB * CC * DD) * sizeof(float);

    dim3 gS(NSPLIT, BB);
    if (ws_size >= need) {
        k_step1f<<<gS, 256, 0, stream>>>(A, x0, T, PA);            // t1 + T
        k_step<true><<<gS, 256, 0, stream>>>(T, PA, NSPLIT, PB);   // t2
        k_step<true><<<gS, 256, 0, stream>>>(T, PB, NSPLIT, PA);   // t3
        k_step<true><<<gS, 256, 0, stream>>>(T, PA, NSPLIT, PB);   // t4
        k_step<true><<<gS, 256, 0, stream>>>(T, PB, NSPLIT, PA);   // t5
        k_mid<<<BB, 256, 0, stream>>>(PB, PA, acc, Y);             // largest, y
        k_step<true><<<gS, 256, 0, stream>>>(T, Y, 1, PB);         // w
        k_fin2<<<BB, 256, 0, stream>>>(PB, Y, acc);
    } else {
        k_step<false><<<gS, 256, 0, stream>>>(A, x0, 1, PA);
        k_step<false><<<gS, 256, 0, stream>>>(A, PA, NSPLIT, PB);
        k_step<false><<<gS, 256, 0, stream>>>(A, PB, NSPLIT, PA);
        k_step<false><<<gS, 256, 0, stream>>>(A, PA, NSPLIT, PB);
        k_step<false><<<gS, 256, 0, stream>>>(A, PB, NSPLIT, PA);
        k_mid<<<BB, 256, 0, stream>>>(PB, PA, acc, Y);
        k_step<false><<<gS, 256, 0, stream>>>(A, Y, 1, PB);
        k_fin2<<<BB, 256, 0, stream>>>(PB, Y, acc);
    }
    k_out<<<1, 64, 0, stream>>>(acc, out);
}